// Round 1
// baseline (200.930 us; speedup 1.0000x reference)
//
#include <hip/hip_runtime.h>

typedef __attribute__((ext_vector_type(8))) short short8;
typedef __attribute__((ext_vector_type(4))) float f32x4;

#define NPOS 32768
#define KDIM 512
#define NCT  30          // conv n-tiles (480 padded cols)
#define CHUNK_BYTES 30720 // one K-chunk (32 k) of conv B in frag order

// ---- bf16 helpers (RNE) ----
__device__ __forceinline__ unsigned short f2bf(float x) {
    unsigned u = __float_as_uint(x);
    return (unsigned short)((u + 0x7FFFu + ((u >> 16) & 1u)) >> 16);
}
__device__ __forceinline__ float bf2f(unsigned short h) {
    return __uint_as_float(((unsigned)h) << 16);
}

// ---- async global->LDS 16B stage: g is per-lane, l is wave-uniform base ----
__device__ __forceinline__ void stage16(const void* g, void* l, int lane) {
    __builtin_amdgcn_global_load_lds(
        (const __attribute__((address_space(1))) unsigned int*)g,
        (__attribute__((address_space(3))) unsigned int*)l, 16, 0, 0);
}

// ===========================================================================
// Prep: swizzle all weights into MFMA B-fragment order (bf16).
// B-frag (16x16x32): lane l holds B[k0 + (l>>4)*8 + i][n0 + (l&15)], i=0..7.
// Conv B: 512 x 480 banded; col blocks (pad to 16): f1@0(32) f2@32(64)
// f3@96(80) f4@176(80) f5@256(80) f6@336(80) f7@416(64). col=FB+oc*NP+p.
// ===========================================================================
__global__ void prep_kernel(const float* __restrict__ w1, const float* __restrict__ w2,
                            const float* __restrict__ w3, const float* __restrict__ w4,
                            const float* __restrict__ w5, const float* __restrict__ w6,
                            const float* __restrict__ w7, const float* __restrict__ hw1,
                            const float* __restrict__ hw2, const float* __restrict__ pw,
                            unsigned short* __restrict__ WC, unsigned short* __restrict__ W1s,
                            unsigned short* __restrict__ W2s, unsigned short* __restrict__ Ps) {
    int gid = blockIdx.x * 256 + threadIdx.x;
    if (gid < 245760) {                      // conv: 512*480
        int k = gid / 480, col = gid % 480;
        const float* wp; int cbnd, NP, C, W;
        if (col < 32)       { wp = w1; cbnd = 0;   NP = 8; C = 4;  W = 1; }
        else if (col < 96)  { wp = w2; cbnd = 32;  NP = 7; C = 8;  W = 2; }
        else if (col < 176) { wp = w3; cbnd = 96;  NP = 6; C = 12; W = 3; }
        else if (col < 256) { wp = w4; cbnd = 176; NP = 5; C = 16; W = 4; }
        else if (col < 336) { wp = w5; cbnd = 256; NP = 4; C = 20; W = 5; }
        else if (col < 416) { wp = w6; cbnd = 336; NP = 3; C = 24; W = 6; }
        else                { wp = w7; cbnd = 416; NP = 2; C = 28; W = 7; }
        int c2 = col - cbnd, oc = c2 / NP, p = c2 - oc * NP;
        int j = k >> 6, e = k & 63, dk = j - p;
        float v = 0.f;
        if (oc < C && dk >= 0 && dk < W) v = wp[(oc * 64 + e) * W + dk];
        int q = k >> 5, kr = k & 31;
        WC[((q * NCT + (col >> 4)) * 64 + ((kr >> 3) * 16 + (col & 15))) * 8 + (kr & 7)] = f2bf(v);
    } else if (gid < 245760 + 57344) {       // highway: 2 x (128*224)
        int x = gid - 245760;
        const float* src = (x < 28672) ? hw1 : hw2;
        unsigned short* dst = (x < 28672) ? W1s : W2s;
        if (x >= 28672) x -= 28672;
        int k = x / 224, n = x % 224;
        float v = (k < 112) ? src[n * 112 + k] : 0.f;
        int q = k >> 5, kr = k & 31;
        dst[((q * 14 + (n >> 4)) * 64 + ((kr >> 3) * 16 + (n & 15))) * 8 + (kr & 7)] = f2bf(v);
    } else if (gid < 245760 + 57344 + 65536) { // proj: 128*512
        int x = gid - 303104;
        int k = x / 512, n = x % 512;
        float v = (k < 112) ? pw[n * 112 + k] : 0.f;
        int q = k >> 5, kr = k & 31;
        Ps[((q * 32 + (n >> 4)) * 64 + ((kr >> 3) * 16 + (n & 15))) * 8 + (kr & 7)] = f2bf(v);
    }
}

// ===========================================================================
// Conv GEMM: [32768,512]x[512,480] bf16 MFMA, fused max/bias/relu epilogue.
// Block: 256 thr / 4 waves, 64 rows (wave w owns rows w*16..+15).
// A-frags in registers (16 k-chunks); B double-buffered via global_load_lds.
// ===========================================================================
template <int T0, int NT>
__device__ __forceinline__ void dump_phase(float* Cb, const f32x4* acc, int wave, int lane) {
    int r0 = wave * 16 + ((lane >> 4) * 4);
    int c0 = lane & 15;
#pragma unroll
    for (int tt = 0; tt < NT; ++tt)
#pragma unroll
        for (int r = 0; r < 4; ++r)
            Cb[(r0 + r) * 161 + tt * 16 + c0] = acc[T0 + tt][r];
}

__device__ void reduce_phase(const float* Cb, unsigned short* ht, int tid,
                             int cA, int NPA, int choffA, int colbA, const float* cbA,
                             int cB, int NPB, int choffB, int colbB, const float* cbB) {
    int noc = cA + cB;
    for (int idx = tid; idx < 64 * noc; idx += 256) {
        int row = idx & 63, ocp = idx >> 6;
        bool isB = ocp >= cA;
        int oc = isB ? ocp - cA : ocp;
        int NP = isB ? NPB : NPA;
        int colb = isB ? colbB : colbA;
        int choff = isB ? choffB : choffA;
        const float* cb = isB ? cbB : cbA;
        const float* src = Cb + row * 161 + colb + oc * NP;
        float m = src[0];
        for (int k = 1; k < NP; ++k) m = fmaxf(m, src[k]);
        float v = fmaxf(m + cb[oc], 0.f);
        ht[row * 128 + choff + oc] = f2bf(v);
    }
}

__global__ __launch_bounds__(256, 2) void conv_gemm(
        const float* __restrict__ feat, const unsigned short* __restrict__ WC,
        const float* cb0, const float* cb1, const float* cb2, const float* cb3,
        const float* cb4, const float* cb5, const float* cb6,
        unsigned short* __restrict__ hg) {
    __shared__ __align__(16) char sm[61440];
    const int tid = threadIdx.x, lane = tid & 63, wave = tid >> 6;
    const int c0 = lane & 15, kq = lane >> 4;
    const int m0 = blockIdx.x * 64;

    // A fragments: 16 k-chunks, fp32 -> bf16 in registers
    const float* arow = feat + (size_t)(m0 + wave * 16 + c0) * KDIM + kq * 8;
    short8 af[16];
#pragma unroll
    for (int q = 0; q < 16; ++q) {
        float t[8];
        *(float4*)(t)     = *(const float4*)(arow + q * 32);
        *(float4*)(t + 4) = *(const float4*)(arow + q * 32 + 4);
        short8 v;
#pragma unroll
        for (int i = 0; i < 8; ++i) v[i] = (short)f2bf(t[i]);
        af[q] = v;
    }

    f32x4 zero = {0.f, 0.f, 0.f, 0.f};
    f32x4 acc[NCT];
#pragma unroll
    for (int t = 0; t < NCT; ++t) acc[t] = zero;

    // prologue: stage chunk 0 into buf 0
    for (int i = tid; i < 1920; i += 256)
        stage16(WC + i * 8, sm + (i - lane) * 16, lane);

#pragma unroll
    for (int q = 0; q < 16; ++q) {
        __syncthreads();
        if (q < 15) {
            const unsigned short* src = WC + (q + 1) * (CHUNK_BYTES / 2);
            char* dst = sm + ((q + 1) & 1) * CHUNK_BYTES;
            for (int i = tid; i < 1920; i += 256)
                stage16(src + i * 8, dst + (i - lane) * 16, lane);
        }
        const char* bb = sm + (q & 1) * CHUNK_BYTES;
#pragma unroll
        for (int t = 0; t < NCT; ++t) {
            short8 b = *(const short8*)(bb + (t * 64 + lane) * 16);
            acc[t] = __builtin_amdgcn_mfma_f32_16x16x32_bf16(af[q], b, acc[t], 0, 0, 0);
        }
    }

    // Epilogue: phased through LDS (phases aligned to filter boundaries)
    float* Cb = (float*)sm;
    unsigned short* ht = (unsigned short*)(sm + 41216);
    __syncthreads();
    for (int i = tid; i < 1024; i += 256)            // zero K-pad cols 112..127
        ht[(i >> 4) * 128 + 112 + (i & 15)] = 0;
    dump_phase<0, 6>(Cb, acc, wave, lane);
    __syncthreads();
    reduce_phase(Cb, ht, tid, 4, 8, 0, 0, cb0, 8, 7, 4, 32, cb1);
    __syncthreads();
    dump_phase<6, 10>(Cb, acc, wave, lane);
    __syncthreads();
    reduce_phase(Cb, ht, tid, 12, 6, 12, 0, cb2, 16, 5, 24, 80, cb3);
    __syncthreads();
    dump_phase<16, 10>(Cb, acc, wave, lane);
    __syncthreads();
    reduce_phase(Cb, ht, tid, 20, 4, 40, 0, cb4, 24, 3, 60, 80, cb5);
    __syncthreads();
    dump_phase<26, 4>(Cb, acc, wave, lane);
    __syncthreads();
    reduce_phase(Cb, ht, tid, 28, 2, 84, 0, cb6, 0, 1, 0, 0, cb6);
    __syncthreads();
    uint4* dst = (uint4*)(hg + (size_t)m0 * 128);
    for (int i = tid; i < 1024; i += 256) dst[i] = ((const uint4*)ht)[i];
}

// ===========================================================================
// Tail: highway1 -> highway2 -> proj fused; h stays in LDS between stages.
// ===========================================================================
__global__ __launch_bounds__(256, 2) void tail_kernel(
        const unsigned short* __restrict__ hg, const unsigned short* __restrict__ W1,
        const unsigned short* __restrict__ W2, const unsigned short* __restrict__ PW,
        const float* __restrict__ hb1, const float* __restrict__ hb2,
        const float* __restrict__ pb, float* __restrict__ out) {
    __shared__ __align__(16) char sm[65536];
    const int tid = threadIdx.x, lane = tid & 63, wave = tid >> 6;
    const int c0 = lane & 15, kq = lane >> 4;
    const int m0 = blockIdx.x * 64;
    f32x4 zero = {0.f, 0.f, 0.f, 0.f};

    // A2 frags from global h
    short8 a2[4];
#pragma unroll
    for (int q = 0; q < 4; ++q)
        a2[q] = *(const short8*)(hg + (size_t)(m0 + wave * 16 + c0) * 128 + q * 32 + kq * 8);

    // GEMM2 (highway1): stage full W1 (57344 B)
    for (int i = tid; i < 3584; i += 256)
        stage16(W1 + i * 8, sm + (i - lane) * 16, lane);
    __syncthreads();
    f32x4 acc2[14];
#pragma unroll
    for (int t = 0; t < 14; ++t) acc2[t] = zero;
#pragma unroll
    for (int t = 0; t < 14; ++t)
#pragma unroll
        for (int q = 0; q < 4; ++q) {
            short8 b = *(const short8*)(sm + ((q * 14 + t) * 64 + lane) * 16);
            acc2[t] = __builtin_amdgcn_mfma_f32_16x16x32_bf16(a2[q], b, acc2[t], 0, 0, 0);
        }
    __syncthreads();   // all W1 reads done before region reuse

    // epilogue2 -> htile (stride 136 bf16; all accesses wave-local rows)
    unsigned short* ht = (unsigned short*)sm;
#pragma unroll
    for (int t = 0; t < 7; ++t) {
        float bp = hb1[t * 16 + c0], bg = hb1[112 + t * 16 + c0];
#pragma unroll
        for (int r = 0; r < 4; ++r) {
            int row = wave * 16 + kq * 4 + r;
            int col = t * 16 + c0;
            float px = acc2[t][r] + bp;
            float gt = acc2[t + 7][r] + bg;
            float g = 1.f / (1.f + __expf(-gt));
            float hres = bf2f(hg[(size_t)(m0 + row) * 128 + col]);
            ht[row * 136 + col] = f2bf(g * hres + (1.f - g) * fmaxf(px, 0.f));
        }
    }
    for (int z = lane; z < 256; z += 64)             // zero own-wave K-pad
        ht[(wave * 16 + (z >> 4)) * 136 + 112 + (z & 15)] = 0;

    short8 a3[4];
#pragma unroll
    for (int q = 0; q < 4; ++q)
        a3[q] = *(const short8*)((const char*)ht + (wave * 16 + c0) * 272 + q * 64 + kq * 16);

    // GEMM3 (highway2): B staged in two 28KB halves at sm+17408
    char* wbuf = sm + 17408;
    f32x4 acc3[14];
#pragma unroll
    for (int t = 0; t < 14; ++t) acc3[t] = zero;
    for (int i = tid; i < 1792; i += 256)
        stage16(W2 + i * 8, wbuf + (i - lane) * 16, lane);
    __syncthreads();
#pragma unroll
    for (int t = 0; t < 14; ++t)
#pragma unroll
        for (int q = 0; q < 2; ++q) {
            short8 b = *(const short8*)(wbuf + ((q * 14 + t) * 64 + lane) * 16);
            acc3[t] = __builtin_amdgcn_mfma_f32_16x16x32_bf16(a3[q], b, acc3[t], 0, 0, 0);
        }
    __syncthreads();   // first-half reads done before restaging same buffer (race fix)
    for (int i = tid; i < 1792; i += 256)
        stage16(W2 + 14336 + i * 8, wbuf + (i - lane) * 16, lane);
    __syncthreads();
#pragma unroll
    for (int t = 0; t < 14; ++t)
#pragma unroll
        for (int q = 0; q < 2; ++q) {
            short8 b = *(const short8*)(wbuf + ((q * 14 + t) * 64 + lane) * 16);
            acc3[t] = __builtin_amdgcn_mfma_f32_16x16x32_bf16(a3[2 + q], b, acc3[t], 0, 0, 0);
        }

    // epilogue3 -> htile in place (same thread reads residual then writes)
#pragma unroll
    for (int t = 0; t < 7; ++t) {
        float bp = hb2[t * 16 + c0], bg = hb2[112 + t * 16 + c0];
#pragma unroll
        for (int r = 0; r < 4; ++r) {
            int row = wave * 16 + kq * 4 + r;
            int col = t * 16 + c0;
            float px = acc3[t][r] + bp;
            float gt = acc3[t + 7][r] + bg;
            float g = 1.f / (1.f + __expf(-gt));
            float hres = bf2f(ht[row * 136 + col]);
            ht[row * 136 + col] = f2bf(g * hres + (1.f - g) * fmaxf(px, 0.f));
        }
    }

    short8 a4[4];
#pragma unroll
    for (int q = 0; q < 4; ++q)
        a4[q] = *(const short8*)((const char*)ht + (wave * 16 + c0) * 272 + q * 64 + kq * 16);

    // GEMM4 (proj): B streamed in 32KB chunks
    f32x4 acc4[32];
#pragma unroll
    for (int t = 0; t < 32; ++t) acc4[t] = zero;
#pragma unroll
    for (int q = 0; q < 4; ++q) {
        __syncthreads();
        for (int i = tid; i < 2048; i += 256)
            stage16(PW + q * 16384 + i * 8, wbuf + (i - lane) * 16, lane);
        __syncthreads();
#pragma unroll
        for (int t = 0; t < 32; ++t) {
            short8 b = *(const short8*)(wbuf + (t * 64 + lane) * 16);
            acc4[t] = __builtin_amdgcn_mfma_f32_16x16x32_bf16(a4[q], b, acc4[t], 0, 0, 0);
        }
    }

    // epilogue4: +bias, coalesced store via LDS transpose (2 halves of 256 cols)
    float* ot = (float*)sm;
#pragma unroll
    for (int half = 0; half < 2; ++half) {
        __syncthreads();
#pragma unroll
        for (int t16 = 0; t16 < 16; ++t16) {
            int col = (half * 16 + t16) * 16 + c0;
            float b = pb[col];
#pragma unroll
            for (int r = 0; r < 4; ++r)
                ot[(wave * 16 + kq * 4 + r) * 256 + t16 * 16 + c0] = acc4[half * 16 + t16][r] + b;
        }
        __syncthreads();
        for (int i = tid; i < 4096; i += 256) {
            int row = i >> 6, c = i & 63;
            *(float4*)(out + (size_t)(m0 + row) * 512 + half * 256 + c * 4) = ((const float4*)ot)[i];
        }
    }
}

// ===========================================================================
extern "C" void kernel_launch(void* const* d_in, const int* in_sizes, int n_in,
                              void* d_out, int out_size, void* d_ws, size_t ws_size,
                              hipStream_t stream) {
    const float* feat = (const float*)d_in[0];
    const float* cw[7];
    const float* cb[7];
    for (int f = 0; f < 7; ++f) {
        cw[f] = (const float*)d_in[1 + 2 * f];
        cb[f] = (const float*)d_in[2 + 2 * f];
    }
    const float* hw_w1 = (const float*)d_in[15];
    const float* hw_b1 = (const float*)d_in[16];
    const float* hw_w2 = (const float*)d_in[17];
    const float* hw_b2 = (const float*)d_in[18];
    const float* pw    = (const float*)d_in[19];
    const float* pb    = (const float*)d_in[20];
    float* out = (float*)d_out;

    char* ws = (char*)d_ws;
    unsigned short* WC  = (unsigned short*)ws;                  // 491,520 B
    unsigned short* W1s = (unsigned short*)(ws + 491520);       //  57,344 B
    unsigned short* W2s = (unsigned short*)(ws + 548864);       //  57,344 B
    unsigned short* Ps  = (unsigned short*)(ws + 606208);       // 131,072 B
    unsigned short* hg  = (unsigned short*)(ws + 737280);       // 8,388,608 B

    prep_kernel<<<1440, 256, 0, stream>>>(cw[0], cw[1], cw[2], cw[3], cw[4], cw[5], cw[6],
                                          hw_w1, hw_w2, pw, WC, W1s, W2s, Ps);
    conv_gemm<<<512, 256, 0, stream>>>(feat, WC, cb[0], cb[1], cb[2], cb[3], cb[4], cb[5], cb[6], hg);
    tail_kernel<<<512, 256, 0, stream>>>(hg, W1s, W2s, Ps, hw_b1, hw_b2, pb, out);
}

// Round 2
// 192.807 us; speedup vs baseline: 1.0421x; 1.0421x over previous
//
#include <hip/hip_runtime.h>

typedef __attribute__((ext_vector_type(8))) short short8;
typedef __attribute__((ext_vector_type(4))) float f32x4;

#define NPOS 32768
#define KDIM 512
#define NCT  30          // conv n-tiles (480 padded cols)
#define CHUNK_BYTES 30720 // one K-chunk (32 k) of conv B in frag order

// ---- bf16 helpers (RNE) ----
__device__ __forceinline__ unsigned short f2bf(float x) {
    unsigned u = __float_as_uint(x);
    return (unsigned short)((u + 0x7FFFu + ((u >> 16) & 1u)) >> 16);
}
__device__ __forceinline__ float bf2f(unsigned short h) {
    return __uint_as_float(((unsigned)h) << 16);
}

// ---- async global->LDS 16B stage: g is per-lane, l is wave-uniform base ----
__device__ __forceinline__ void stage16(const void* g, void* l, int lane) {
    __builtin_amdgcn_global_load_lds(
        (const __attribute__((address_space(1))) unsigned int*)g,
        (__attribute__((address_space(3))) unsigned int*)l, 16, 0, 0);
}

// ===========================================================================
// Prep: swizzle all weights into MFMA B-fragment order (bf16).
// B-frag (16x16x32): lane l holds B[k0 + (l>>4)*8 + i][n0 + (l&15)], i=0..7.
// Conv B: 512 x 480 banded; col blocks (pad to 16): f1@0(32) f2@32(64)
// f3@96(80) f4@176(80) f5@256(80) f6@336(80) f7@416(64). col=FB+oc*NP+p.
// ===========================================================================
__global__ void prep_kernel(const float* __restrict__ w1, const float* __restrict__ w2,
                            const float* __restrict__ w3, const float* __restrict__ w4,
                            const float* __restrict__ w5, const float* __restrict__ w6,
                            const float* __restrict__ w7, const float* __restrict__ hw1,
                            const float* __restrict__ hw2, const float* __restrict__ pw,
                            unsigned short* __restrict__ WC, unsigned short* __restrict__ W1s,
                            unsigned short* __restrict__ W2s, unsigned short* __restrict__ Ps) {
    int gid = blockIdx.x * 256 + threadIdx.x;
    if (gid < 245760) {                      // conv: 512*480
        int k = gid / 480, col = gid % 480;
        const float* wp; int cbnd, NP, C, W;
        if (col < 32)       { wp = w1; cbnd = 0;   NP = 8; C = 4;  W = 1; }
        else if (col < 96)  { wp = w2; cbnd = 32;  NP = 7; C = 8;  W = 2; }
        else if (col < 176) { wp = w3; cbnd = 96;  NP = 6; C = 12; W = 3; }
        else if (col < 256) { wp = w4; cbnd = 176; NP = 5; C = 16; W = 4; }
        else if (col < 336) { wp = w5; cbnd = 256; NP = 4; C = 20; W = 5; }
        else if (col < 416) { wp = w6; cbnd = 336; NP = 3; C = 24; W = 6; }
        else                { wp = w7; cbnd = 416; NP = 2; C = 28; W = 7; }
        int c2 = col - cbnd, oc = c2 / NP, p = c2 - oc * NP;
        int j = k >> 6, e = k & 63, dk = j - p;
        float v = 0.f;
        if (oc < C && dk >= 0 && dk < W) v = wp[(oc * 64 + e) * W + dk];
        int q = k >> 5, kr = k & 31;
        WC[((q * NCT + (col >> 4)) * 64 + ((kr >> 3) * 16 + (col & 15))) * 8 + (kr & 7)] = f2bf(v);
    } else if (gid < 245760 + 57344) {       // highway: 2 x (128*224)
        int x = gid - 245760;
        const float* src = (x < 28672) ? hw1 : hw2;
        unsigned short* dst = (x < 28672) ? W1s : W2s;
        if (x >= 28672) x -= 28672;
        int k = x / 224, n = x % 224;
        float v = (k < 112) ? src[n * 112 + k] : 0.f;
        int q = k >> 5, kr = k & 31;
        dst[((q * 14 + (n >> 4)) * 64 + ((kr >> 3) * 16 + (n & 15))) * 8 + (kr & 7)] = f2bf(v);
    } else if (gid < 245760 + 57344 + 65536) { // proj: 128*512
        int x = gid - 303104;
        int k = x / 512, n = x % 512;
        float v = (k < 112) ? pw[n * 112 + k] : 0.f;
        int q = k >> 5, kr = k & 31;
        Ps[((q * 32 + (n >> 4)) * 64 + ((kr >> 3) * 16 + (n & 15))) * 8 + (kr & 7)] = f2bf(v);
    }
}

// ===========================================================================
// Fused kernel: conv GEMM + max/relu + highway1 + highway2 + proj.
// Block: 256 thr / 4 waves, 64 rows. h never leaves LDS.
// LDS map (65536 B):
//   conv loop : [0,61440) B double-buffer (2 x 30720)
//   epilogue  : Cb [0,41216) f32, ht @41216 stride 136 shorts (17408 B)
//   gemm2/3   : wb 2 x 14336 @[0,28672); ht persists @41216
//   gemm4     : pwb 2 x 16384 @[0,32768); ht persists @41216
//   epilogue4 : ot [0,65536) f32 (ht dead)
// ===========================================================================
template <int T0, int NT>
__device__ __forceinline__ void dump_phase(float* Cb, const f32x4* acc, int wave, int lane) {
    int r0 = wave * 16 + ((lane >> 4) * 4);
    int c0 = lane & 15;
#pragma unroll
    for (int tt = 0; tt < NT; ++tt)
#pragma unroll
        for (int r = 0; r < 4; ++r)
            Cb[(r0 + r) * 161 + tt * 16 + c0] = acc[T0 + tt][r];
}

__device__ void reduce_phase(const float* Cb, unsigned short* ht, int tid,
                             int cA, int NPA, int choffA, int colbA, const float* cbA,
                             int cB, int NPB, int choffB, int colbB, const float* cbB) {
    int noc = cA + cB;
    for (int idx = tid; idx < 64 * noc; idx += 256) {
        int row = idx & 63, ocp = idx >> 6;
        bool isB = ocp >= cA;
        int oc = isB ? ocp - cA : ocp;
        int NP = isB ? NPB : NPA;
        int colb = isB ? colbB : colbA;
        int choff = isB ? choffB : choffA;
        const float* cb = isB ? cbB : cbA;
        const float* src = Cb + row * 161 + colb + oc * NP;
        float m = src[0];
        for (int k = 1; k < NP; ++k) m = fmaxf(m, src[k]);
        float v = fmaxf(m + cb[oc], 0.f);
        ht[row * 136 + choff + oc] = f2bf(v);   // stride 136 (bank-conflict-free frags)
    }
}

__global__ __launch_bounds__(256, 2) void fused_kernel(
        const float* __restrict__ feat, const unsigned short* __restrict__ WC,
        const float* cb0, const float* cb1, const float* cb2, const float* cb3,
        const float* cb4, const float* cb5, const float* cb6,
        const unsigned short* __restrict__ W1, const unsigned short* __restrict__ W2,
        const unsigned short* __restrict__ PW,
        const float* __restrict__ hb1, const float* __restrict__ hb2,
        const float* __restrict__ pb, float* __restrict__ out) {
    __shared__ __align__(16) char sm[65536];
    const int tid = threadIdx.x, lane = tid & 63, wave = tid >> 6;
    const int c0 = lane & 15, kq = lane >> 4;
    const int m0 = blockIdx.x * 64;
    f32x4 zero = {0.f, 0.f, 0.f, 0.f};

    // ---------------- conv GEMM ----------------
    // A fragments: 16 k-chunks, fp32 -> bf16 in registers
    const float* arow = feat + (size_t)(m0 + wave * 16 + c0) * KDIM + kq * 8;
    short8 af[16];
#pragma unroll
    for (int q = 0; q < 16; ++q) {
        float t[8];
        *(float4*)(t)     = *(const float4*)(arow + q * 32);
        *(float4*)(t + 4) = *(const float4*)(arow + q * 32 + 4);
        short8 v;
#pragma unroll
        for (int i = 0; i < 8; ++i) v[i] = (short)f2bf(t[i]);
        af[q] = v;
    }

    f32x4 acc[NCT];
#pragma unroll
    for (int t = 0; t < NCT; ++t) acc[t] = zero;

    // prologue: stage chunk 0 into buf 0
    for (int i = tid; i < 1920; i += 256)
        stage16(WC + i * 8, sm + (i - lane) * 16, lane);

#pragma unroll
    for (int q = 0; q < 16; ++q) {
        __syncthreads();
        if (q < 15) {
            const unsigned short* src = WC + (q + 1) * (CHUNK_BYTES / 2);
            char* dst = sm + ((q + 1) & 1) * CHUNK_BYTES;
            for (int i = tid; i < 1920; i += 256)
                stage16(src + i * 8, dst + (i - lane) * 16, lane);
        }
        const char* bb = sm + (q & 1) * CHUNK_BYTES;
#pragma unroll
        for (int t = 0; t < NCT; ++t) {
            short8 b = *(const short8*)(bb + (t * 64 + lane) * 16);
            acc[t] = __builtin_amdgcn_mfma_f32_16x16x32_bf16(af[q], b, acc[t], 0, 0, 0);
        }
    }

    // ---------------- conv epilogue (max/bias/relu -> ht in LDS) ----------------
    float* Cb = (float*)sm;
    unsigned short* ht = (unsigned short*)(sm + 41216);   // 64 rows x 136 shorts
    __syncthreads();
    for (int i = tid; i < 1024; i += 256)                 // zero K-pad cols 112..127
        ht[(i >> 4) * 136 + 112 + (i & 15)] = 0;
    dump_phase<0, 6>(Cb, acc, wave, lane);
    __syncthreads();
    reduce_phase(Cb, ht, tid, 4, 8, 0, 0, cb0, 8, 7, 4, 32, cb1);
    __syncthreads();
    dump_phase<6, 10>(Cb, acc, wave, lane);
    __syncthreads();
    reduce_phase(Cb, ht, tid, 12, 6, 12, 0, cb2, 16, 5, 24, 80, cb3);
    __syncthreads();
    dump_phase<16, 10>(Cb, acc, wave, lane);
    __syncthreads();
    reduce_phase(Cb, ht, tid, 20, 4, 40, 0, cb4, 24, 3, 60, 80, cb5);
    __syncthreads();
    dump_phase<26, 4>(Cb, acc, wave, lane);
    __syncthreads();
    reduce_phase(Cb, ht, tid, 28, 2, 84, 0, cb6, 0, 1, 0, 0, cb6);
    __syncthreads();                                      // ht complete

    // ---------------- GEMM2 (highway1), W1 in 4 dbuf k-chunks ----------------
    char* wb = sm;                                        // 2 x 14336
    // A2 frags from LDS ht (stride 136 shorts = 272 B)
    short8 a2[4];
#pragma unroll
    for (int q = 0; q < 4; ++q)
        a2[q] = *(const short8*)((const char*)ht + (wave * 16 + c0) * 272 + q * 64 + kq * 16);
    // stage chunk 0 (region [0,14336): Cb reads drained at barrier above)
    for (int i = tid; i < 896; i += 256)
        stage16(W1 + i * 8, wb + (i - lane) * 16, lane);

    f32x4 acc2[14];
#pragma unroll
    for (int t = 0; t < 14; ++t) acc2[t] = zero;
#pragma unroll
    for (int q = 0; q < 4; ++q) {
        __syncthreads();
        if (q < 3) {
            const unsigned short* src = W1 + (q + 1) * 7168;
            char* dst = wb + ((q + 1) & 1) * 14336;
            for (int i = tid; i < 896; i += 256)
                stage16(src + i * 8, dst + (i - lane) * 16, lane);
        }
        const char* bb = wb + (q & 1) * 14336;
#pragma unroll
        for (int t = 0; t < 14; ++t) {
            short8 b = *(const short8*)(bb + (t * 64 + lane) * 16);
            acc2[t] = __builtin_amdgcn_mfma_f32_16x16x32_bf16(a2[q], b, acc2[t], 0, 0, 0);
        }
    }

    // prefetch W2 chunk 0 into wb[0] (its last readers drained at q=3 barrier)
    for (int i = tid; i < 896; i += 256)
        stage16(W2 + i * 8, wb + (i - lane) * 16, lane);

    // epilogue2 -> ht in place (thread reads own residual then writes)
#pragma unroll
    for (int t = 0; t < 7; ++t) {
        float bp = hb1[t * 16 + c0], bg = hb1[112 + t * 16 + c0];
#pragma unroll
        for (int r = 0; r < 4; ++r) {
            int row = wave * 16 + kq * 4 + r;
            int col = t * 16 + c0;
            float px = acc2[t][r] + bp;
            float gt = acc2[t + 7][r] + bg;
            float g = 1.f / (1.f + __expf(-gt));
            float hres = bf2f(ht[row * 136 + col]);
            ht[row * 136 + col] = f2bf(g * hres + (1.f - g) * fmaxf(px, 0.f));
        }
    }
    __syncthreads();                                      // ht visible + W2c0 drained

    // ---------------- GEMM3 (highway2), same dbuf pattern ----------------
    short8 a3[4];
#pragma unroll
    for (int q = 0; q < 4; ++q)
        a3[q] = *(const short8*)((const char*)ht + (wave * 16 + c0) * 272 + q * 64 + kq * 16);

    f32x4 acc3[14];
#pragma unroll
    for (int t = 0; t < 14; ++t) acc3[t] = zero;
#pragma unroll
    for (int q = 0; q < 4; ++q) {
        __syncthreads();
        if (q < 3) {
            const unsigned short* src = W2 + (q + 1) * 7168;
            char* dst = wb + ((q + 1) & 1) * 14336;
            for (int i = tid; i < 896; i += 256)
                stage16(src + i * 8, dst + (i - lane) * 16, lane);
        }
        const char* bb = wb + (q & 1) * 14336;
#pragma unroll
        for (int t = 0; t < 14; ++t) {
            short8 b = *(const short8*)(bb + (t * 64 + lane) * 16);
            acc3[t] = __builtin_amdgcn_mfma_f32_16x16x32_bf16(a3[q], b, acc3[t], 0, 0, 0);
        }
    }

    // epilogue3 -> ht in place
#pragma unroll
    for (int t = 0; t < 7; ++t) {
        float bp = hb2[t * 16 + c0], bg = hb2[112 + t * 16 + c0];
#pragma unroll
        for (int r = 0; r < 4; ++r) {
            int row = wave * 16 + kq * 4 + r;
            int col = t * 16 + c0;
            float px = acc3[t][r] + bp;
            float gt = acc3[t + 7][r] + bg;
            float g = 1.f / (1.f + __expf(-gt));
            float hres = bf2f(ht[row * 136 + col]);
            ht[row * 136 + col] = f2bf(g * hres + (1.f - g) * fmaxf(px, 0.f));
        }
    }
    __syncthreads();                                      // drain gemm3 ds_reads; ht visible

    // ---------------- GEMM4 (proj), PW in 8 dbuf chunks of 16 KB ----------------
    short8 a4[4];
#pragma unroll
    for (int q = 0; q < 4; ++q)
        a4[q] = *(const short8*)((const char*)ht + (wave * 16 + c0) * 272 + q * 64 + kq * 16);

    char* pwb = sm;                                       // 2 x 16384
    // chunk c: k-quarter q=c>>1, n-half h=c&1; 16 tiles of 1024 B
    for (int i = tid; i < 1024; i += 256)
        stage16(PW + i * 8, pwb + (i - lane) * 16, lane);

    f32x4 acc4[32];
#pragma unroll
    for (int t = 0; t < 32; ++t) acc4[t] = zero;
#pragma unroll
    for (int c = 0; c < 8; ++c) {
        __syncthreads();
        if (c < 7) {
            const unsigned short* src = PW + (c + 1) * 8192;
            char* dst = pwb + ((c + 1) & 1) * 16384;
            for (int i = tid; i < 1024; i += 256)
                stage16(src + i * 8, dst + (i - lane) * 16, lane);
        }
        const char* bb = pwb + (c & 1) * 16384;
#pragma unroll
        for (int tt = 0; tt < 16; ++tt) {
            short8 b = *(const short8*)(bb + (tt * 64 + lane) * 16);
            acc4[(c & 1) * 16 + tt] =
                __builtin_amdgcn_mfma_f32_16x16x32_bf16(a4[c >> 1], b, acc4[(c & 1) * 16 + tt], 0, 0, 0);
        }
    }

    // ---------------- epilogue4: +bias, coalesced store via LDS transpose ----------------
    float* ot = (float*)sm;
#pragma unroll
    for (int half = 0; half < 2; ++half) {
        __syncthreads();
#pragma unroll
        for (int t16 = 0; t16 < 16; ++t16) {
            int col = (half * 16 + t16) * 16 + c0;
            float b = pb[col];
#pragma unroll
            for (int r = 0; r < 4; ++r)
                ot[(wave * 16 + kq * 4 + r) * 256 + t16 * 16 + c0] = acc4[half * 16 + t16][r] + b;
        }
        __syncthreads();
        for (int i = tid; i < 4096; i += 256) {
            int row = i >> 6, c = i & 63;
            *(float4*)(out + (size_t)(m0 + row) * 512 + half * 256 + c * 4) = ((const float4*)ot)[i];
        }
    }
}

// ===========================================================================
extern "C" void kernel_launch(void* const* d_in, const int* in_sizes, int n_in,
                              void* d_out, int out_size, void* d_ws, size_t ws_size,
                              hipStream_t stream) {
    const float* feat = (const float*)d_in[0];
    const float* cw[7];
    const float* cb[7];
    for (int f = 0; f < 7; ++f) {
        cw[f] = (const float*)d_in[1 + 2 * f];
        cb[f] = (const float*)d_in[2 + 2 * f];
    }
    const float* hw_w1 = (const float*)d_in[15];
    const float* hw_b1 = (const float*)d_in[16];
    const float* hw_w2 = (const float*)d_in[17];
    const float* hw_b2 = (const float*)d_in[18];
    const float* pw    = (const float*)d_in[19];
    const float* pb    = (const float*)d_in[20];
    float* out = (float*)d_out;

    char* ws = (char*)d_ws;
    unsigned short* WC  = (unsigned short*)ws;                  // 491,520 B
    unsigned short* W1s = (unsigned short*)(ws + 491520);       //  57,344 B
    unsigned short* W2s = (unsigned short*)(ws + 548864);       //  57,344 B
    unsigned short* Ps  = (unsigned short*)(ws + 606208);       // 131,072 B

    prep_kernel<<<1440, 256, 0, stream>>>(cw[0], cw[1], cw[2], cw[3], cw[4], cw[5], cw[6],
                                          hw_w1, hw_w2, pw, WC, W1s, W2s, Ps);
    fused_kernel<<<512, 256, 0, stream>>>(feat, WC, cb[0], cb[1], cb[2], cb[3], cb[4], cb[5], cb[6],
                                          W1s, W2s, Ps, hw_b1, hw_b2, pb, out);
}

// Round 3
// 192.107 us; speedup vs baseline: 1.0459x; 1.0036x over previous
//
#include <hip/hip_runtime.h>

typedef __attribute__((ext_vector_type(8))) short short8;
typedef __attribute__((ext_vector_type(4))) float f32x4;

#define KDIM 512
#define NCT  30          // conv n-tiles (480 cols, padded to 32 tiles in chunk)
#define BCHUNK 32768     // padded conv B chunk bytes (32 tiles; 30 valid)

// ---- bf16 helpers (RNE) ----
__device__ __forceinline__ unsigned short f2bf(float x) {
    unsigned u = __float_as_uint(x);
    return (unsigned short)((u + 0x7FFFu + ((u >> 16) & 1u)) >> 16);
}
__device__ __forceinline__ float bf2f(unsigned short h) {
    return __uint_as_float(((unsigned)h) << 16);
}

// ---- async global->LDS 16B stage: g is per-lane, l is wave-uniform base ----
__device__ __forceinline__ void stage16(const void* g, void* l, int lane) {
    __builtin_amdgcn_global_load_lds(
        (const __attribute__((address_space(1))) unsigned int*)g,
        (__attribute__((address_space(3))) unsigned int*)l, 16, 0, 0);
}

// ===========================================================================
// Prep: swizzle all weights into MFMA B-fragment order (bf16).
// Chunk strides PADDED so staging is a uniform 16B x 2048 (conv) / 1024 (tail)
// per chunk: conv chunk = 16384 shorts (32 tiles, 30 valid); W1/W2 chunk =
// 8192 shorts (16 tiles, 14 valid); proj chunk = 8192 shorts (16 tiles).
// Pad tiles are never read by the MFMA loops.
// ===========================================================================
__global__ void prep_kernel(const float* __restrict__ w1, const float* __restrict__ w2,
                            const float* __restrict__ w3, const float* __restrict__ w4,
                            const float* __restrict__ w5, const float* __restrict__ w6,
                            const float* __restrict__ w7, const float* __restrict__ hw1,
                            const float* __restrict__ hw2, const float* __restrict__ pw,
                            unsigned short* __restrict__ WC, unsigned short* __restrict__ W1s,
                            unsigned short* __restrict__ W2s, unsigned short* __restrict__ Ps) {
    int gid = blockIdx.x * 256 + threadIdx.x;
    if (gid < 245760) {                      // conv: 512*480
        int k = gid / 480, col = gid % 480;
        const float* wp; int cbnd, NP, C, W;
        if (col < 32)       { wp = w1; cbnd = 0;   NP = 8; C = 4;  W = 1; }
        else if (col < 96)  { wp = w2; cbnd = 32;  NP = 7; C = 8;  W = 2; }
        else if (col < 176) { wp = w3; cbnd = 96;  NP = 6; C = 12; W = 3; }
        else if (col < 256) { wp = w4; cbnd = 176; NP = 5; C = 16; W = 4; }
        else if (col < 336) { wp = w5; cbnd = 256; NP = 4; C = 20; W = 5; }
        else if (col < 416) { wp = w6; cbnd = 336; NP = 3; C = 24; W = 6; }
        else                { wp = w7; cbnd = 416; NP = 2; C = 28; W = 7; }
        int c2 = col - cbnd, oc = c2 / NP, p = c2 - oc * NP;
        int j = k >> 6, e = k & 63, dk = j - p;
        float v = 0.f;
        if (oc < C && dk >= 0 && dk < W) v = wp[(oc * 64 + e) * W + dk];
        int q = k >> 5, kr = k & 31;
        WC[q * 16384 + ((col >> 4) * 64 + ((kr >> 3) * 16 + (col & 15))) * 8 + (kr & 7)] = f2bf(v);
    } else if (gid < 245760 + 57344) {       // highway: 2 x (128*224)
        int x = gid - 245760;
        const float* src = (x < 28672) ? hw1 : hw2;
        unsigned short* dst = (x < 28672) ? W1s : W2s;
        if (x >= 28672) x -= 28672;
        int k = x / 224, n = x % 224;
        float v = (k < 112) ? src[n * 112 + k] : 0.f;
        int q = k >> 5, kr = k & 31;
        dst[q * 8192 + ((n >> 4) * 64 + ((kr >> 3) * 16 + (n & 15))) * 8 + (kr & 7)] = f2bf(v);
    } else if (gid < 245760 + 57344 + 65536) { // proj: 128*512
        int x = gid - 303104;
        int k = x / 512, n = x % 512;
        float v = (k < 112) ? pw[n * 112 + k] : 0.f;
        int q = k >> 5, kr = k & 31;
        Ps[((q * 32 + (n >> 4)) * 64 + ((kr >> 3) * 16 + (n & 15))) * 8 + (kr & 7)] = f2bf(v);
    }
}

// ===========================================================================
// Fused kernel: conv GEMM + max/relu + highway1 + highway2 + proj.
// All staged loops use raw s_barrier + COUNTED vmcnt (no vmcnt(0) drain in
// steady state): issue stage(q+1) -> vmcnt(own-count) -> barrier -> compute
// -> lgkmcnt(0) -> barrier. Per-thread stage counts are uniform by chunk
// padding: conv 8 loads (vmcnt 8), tail GEMMs 4 loads (vmcnt 4).
// LDS map (65536 B):
//   conv loop : B dbuf 2 x 32768
//   epilogue  : Cb [0,41216) f32, ht @41216 stride 136 shorts (17408 B)
//   gemm2/3/4 : wb/pwb dbuf 2 x 16384 @[0,32768); ht persists @41216
//   epilogue4 : ot [0,65536) f32 (ht dead)
// ===========================================================================
template <int T0, int NT>
__device__ __forceinline__ void dump_phase(float* Cb, const f32x4* acc, int wave, int lane) {
    int r0 = wave * 16 + ((lane >> 4) * 4);
    int c0 = lane & 15;
#pragma unroll
    for (int tt = 0; tt < NT; ++tt)
#pragma unroll
        for (int r = 0; r < 4; ++r)
            Cb[(r0 + r) * 161 + tt * 16 + c0] = acc[T0 + tt][r];
}

__device__ void reduce_phase(const float* Cb, unsigned short* ht, int tid,
                             int cA, int NPA, int choffA, int colbA, const float* cbA,
                             int cB, int NPB, int choffB, int colbB, const float* cbB) {
    int noc = cA + cB;
    for (int idx = tid; idx < 64 * noc; idx += 256) {
        int row = idx & 63, ocp = idx >> 6;
        bool isB = ocp >= cA;
        int oc = isB ? ocp - cA : ocp;
        int NP = isB ? NPB : NPA;
        int colb = isB ? colbB : colbA;
        int choff = isB ? choffB : choffA;
        const float* cb = isB ? cbB : cbA;
        const float* src = Cb + row * 161 + colb + oc * NP;
        float m = src[0];
        for (int k = 1; k < NP; ++k) m = fmaxf(m, src[k]);
        float v = fmaxf(m + cb[oc], 0.f);
        ht[row * 136 + choff + oc] = f2bf(v);
    }
}

__global__ __launch_bounds__(256, 2) void fused_kernel(
        const float* __restrict__ feat, const unsigned short* __restrict__ WC,
        const float* cb0, const float* cb1, const float* cb2, const float* cb3,
        const float* cb4, const float* cb5, const float* cb6,
        const unsigned short* __restrict__ W1, const unsigned short* __restrict__ W2,
        const unsigned short* __restrict__ PW,
        const float* __restrict__ hb1, const float* __restrict__ hb2,
        const float* __restrict__ pb, float* __restrict__ out) {
    __shared__ __align__(16) char sm[65536];
    const int tid = threadIdx.x, lane = tid & 63, wave = tid >> 6;
    const int c0 = lane & 15, kq = lane >> 4;
    const int m0 = blockIdx.x * 64;
    f32x4 zero = {0.f, 0.f, 0.f, 0.f};

    // ---------------- conv GEMM ----------------
    const float* arow = feat + (size_t)(m0 + wave * 16 + c0) * KDIM + kq * 8;
    short8 af[16];
#pragma unroll
    for (int q = 0; q < 16; ++q) {
        float t[8];
        *(float4*)(t)     = *(const float4*)(arow + q * 32);
        *(float4*)(t + 4) = *(const float4*)(arow + q * 32 + 4);
        short8 v;
#pragma unroll
        for (int i = 0; i < 8; ++i) v[i] = (short)f2bf(t[i]);
        af[q] = v;
    }

    f32x4 acc[NCT];
#pragma unroll
    for (int t = 0; t < NCT; ++t) acc[t] = zero;

    // prologue: stage chunk 0 into buf 0 (8 loads/thread, uniform)
    for (int i = tid; i < 2048; i += 256)
        stage16(WC + i * 8, sm + (i - lane) * 16, lane);

#pragma unroll
    for (int q = 0; q < 16; ++q) {
        if (q < 15) {
            const unsigned short* src = WC + (q + 1) * 16384;
            char* dst = sm + ((q + 1) & 1) * BCHUNK;
            for (int i = tid; i < 2048; i += 256)
                stage16(src + i * 8, dst + (i - lane) * 16, lane);
            asm volatile("s_waitcnt vmcnt(8)" ::: "memory");   // chunk q landed; q+1 in flight
        } else {
            asm volatile("s_waitcnt vmcnt(0)" ::: "memory");
        }
        __builtin_amdgcn_s_barrier();
        const char* bb = sm + (q & 1) * BCHUNK;
        __builtin_amdgcn_s_setprio(1);
#pragma unroll
        for (int t = 0; t < NCT; ++t) {
            short8 b = *(const short8*)(bb + (t * 64 + lane) * 16);
            acc[t] = __builtin_amdgcn_mfma_f32_16x16x32_bf16(af[q], b, acc[t], 0, 0, 0);
        }
        __builtin_amdgcn_s_setprio(0);
        asm volatile("s_waitcnt lgkmcnt(0)" ::: "memory");     // reads of buf done
        __builtin_amdgcn_s_barrier();                          // safe to restage next iter
    }

    // ---------------- conv epilogue (max/bias/relu -> ht in LDS) ----------------
    float* Cb = (float*)sm;
    unsigned short* ht = (unsigned short*)(sm + 41216);   // 64 rows x 136 shorts
    __syncthreads();
    for (int i = tid; i < 1024; i += 256)                 // zero K-pad cols 112..127
        ht[(i >> 4) * 136 + 112 + (i & 15)] = 0;
    dump_phase<0, 6>(Cb, acc, wave, lane);
    __syncthreads();
    reduce_phase(Cb, ht, tid, 4, 8, 0, 0, cb0, 8, 7, 4, 32, cb1);
    __syncthreads();
    dump_phase<6, 10>(Cb, acc, wave, lane);
    __syncthreads();
    reduce_phase(Cb, ht, tid, 12, 6, 12, 0, cb2, 16, 5, 24, 80, cb3);
    __syncthreads();
    dump_phase<16, 10>(Cb, acc, wave, lane);
    __syncthreads();
    reduce_phase(Cb, ht, tid, 20, 4, 40, 0, cb4, 24, 3, 60, 80, cb5);
    __syncthreads();
    dump_phase<26, 4>(Cb, acc, wave, lane);
    __syncthreads();
    reduce_phase(Cb, ht, tid, 28, 2, 84, 0, cb6, 0, 1, 0, 0, cb6);
    __syncthreads();                                      // ht complete; Cb dead

    // ---------------- GEMM2 (highway1): 4 x 16KB dbuf chunks ----------------
    char* wb = sm;                                        // 2 x 16384
    short8 a2[4];
#pragma unroll
    for (int q = 0; q < 4; ++q)
        a2[q] = *(const short8*)((const char*)ht + (wave * 16 + c0) * 272 + q * 64 + kq * 16);
    for (int i = tid; i < 1024; i += 256)                 // stage W1 chunk 0
        stage16(W1 + i * 8, wb + (i - lane) * 16, lane);

    f32x4 acc2[14];
#pragma unroll
    for (int t = 0; t < 14; ++t) acc2[t] = zero;
#pragma unroll
    for (int q = 0; q < 4; ++q) {
        if (q < 3) {
            const unsigned short* src = W1 + (q + 1) * 8192;
            char* dst = wb + ((q + 1) & 1) * 16384;
            for (int i = tid; i < 1024; i += 256)
                stage16(src + i * 8, dst + (i - lane) * 16, lane);
        } else {
            // cross-prefetch W2 chunk 0 into wb buf0 (this iter reads buf1)
            for (int i = tid; i < 1024; i += 256)
                stage16(W2 + i * 8, wb + (i - lane) * 16, lane);
        }
        asm volatile("s_waitcnt vmcnt(4)" ::: "memory");
        __builtin_amdgcn_s_barrier();
        const char* bb = wb + (q & 1) * 16384;
#pragma unroll
        for (int t = 0; t < 14; ++t) {
            short8 b = *(const short8*)(bb + (t * 64 + lane) * 16);
            acc2[t] = __builtin_amdgcn_mfma_f32_16x16x32_bf16(a2[q], b, acc2[t], 0, 0, 0);
        }
        asm volatile("s_waitcnt lgkmcnt(0)" ::: "memory");
        __builtin_amdgcn_s_barrier();
    }

    // epilogue2 -> ht in place (wave-local rows; same-wave DS ordering)
#pragma unroll
    for (int t = 0; t < 7; ++t) {
        float bp = hb1[t * 16 + c0], bg = hb1[112 + t * 16 + c0];
#pragma unroll
        for (int r = 0; r < 4; ++r) {
            int row = wave * 16 + kq * 4 + r;
            int col = t * 16 + c0;
            float px = acc2[t][r] + bp;
            float gt = acc2[t + 7][r] + bg;
            float g = 1.f / (1.f + __expf(-gt));
            float hres = bf2f(ht[row * 136 + col]);
            ht[row * 136 + col] = f2bf(g * hres + (1.f - g) * fmaxf(px, 0.f));
        }
    }

    // ---------------- GEMM3 (highway2): W2 chunks (c0 already in flight) ----------------
    short8 a3[4];
#pragma unroll
    for (int q = 0; q < 4; ++q)
        a3[q] = *(const short8*)((const char*)ht + (wave * 16 + c0) * 272 + q * 64 + kq * 16);

    f32x4 acc3[14];
#pragma unroll
    for (int t = 0; t < 14; ++t) acc3[t] = zero;
#pragma unroll
    for (int q = 0; q < 4; ++q) {
        if (q < 3) {
            const unsigned short* src = W2 + (q + 1) * 8192;
            char* dst = wb + ((q + 1) & 1) * 16384;
            for (int i = tid; i < 1024; i += 256)
                stage16(src + i * 8, dst + (i - lane) * 16, lane);
        } else {
            // cross-prefetch PW chunk 0 into pwb buf0 = wb buf0 (this iter reads buf1)
            for (int i = tid; i < 1024; i += 256)
                stage16(PW + i * 8, wb + (i - lane) * 16, lane);
        }
        asm volatile("s_waitcnt vmcnt(4)" ::: "memory");
        __builtin_amdgcn_s_barrier();
        const char* bb = wb + (q & 1) * 16384;
#pragma unroll
        for (int t = 0; t < 14; ++t) {
            short8 b = *(const short8*)(bb + (t * 64 + lane) * 16);
            acc3[t] = __builtin_amdgcn_mfma_f32_16x16x32_bf16(a3[q], b, acc3[t], 0, 0, 0);
        }
        asm volatile("s_waitcnt lgkmcnt(0)" ::: "memory");
        __builtin_amdgcn_s_barrier();
    }

    // epilogue3 -> ht in place (PW chunk 0 latency hides under this)
#pragma unroll
    for (int t = 0; t < 7; ++t) {
        float bp = hb2[t * 16 + c0], bg = hb2[112 + t * 16 + c0];
#pragma unroll
        for (int r = 0; r < 4; ++r) {
            int row = wave * 16 + kq * 4 + r;
            int col = t * 16 + c0;
            float px = acc3[t][r] + bp;
            float gt = acc3[t + 7][r] + bg;
            float g = 1.f / (1.f + __expf(-gt));
            float hres = bf2f(ht[row * 136 + col]);
            ht[row * 136 + col] = f2bf(g * hres + (1.f - g) * fmaxf(px, 0.f));
        }
    }

    // ---------------- GEMM4 (proj): 8 x 16KB dbuf chunks ----------------
    short8 a4[4];
#pragma unroll
    for (int q = 0; q < 4; ++q)
        a4[q] = *(const short8*)((const char*)ht + (wave * 16 + c0) * 272 + q * 64 + kq * 16);

    char* pwb = sm;                                       // 2 x 16384 (buf0 = PW c0)
    f32x4 acc4[32];
#pragma unroll
    for (int t = 0; t < 32; ++t) acc4[t] = zero;
#pragma unroll
    for (int c = 0; c < 8; ++c) {
        if (c < 7) {
            const unsigned short* src = PW + (c + 1) * 8192;
            char* dst = pwb + ((c + 1) & 1) * 16384;
            for (int i = tid; i < 1024; i += 256)
                stage16(src + i * 8, dst + (i - lane) * 16, lane);
            asm volatile("s_waitcnt vmcnt(4)" ::: "memory");
        } else {
            asm volatile("s_waitcnt vmcnt(0)" ::: "memory");
        }
        __builtin_amdgcn_s_barrier();
        const char* bb = pwb + (c & 1) * 16384;
        __builtin_amdgcn_s_setprio(1);
#pragma unroll
        for (int tt = 0; tt < 16; ++tt) {
            short8 b = *(const short8*)(bb + (tt * 64 + lane) * 16);
            acc4[(c & 1) * 16 + tt] =
                __builtin_amdgcn_mfma_f32_16x16x32_bf16(a4[c >> 1], b, acc4[(c & 1) * 16 + tt], 0, 0, 0);
        }
        __builtin_amdgcn_s_setprio(0);
        asm volatile("s_waitcnt lgkmcnt(0)" ::: "memory");
        __builtin_amdgcn_s_barrier();
    }

    // ---------------- epilogue4: +bias, coalesced store via LDS transpose ----------------
    float* ot = (float*)sm;
#pragma unroll
    for (int half = 0; half < 2; ++half) {
        __syncthreads();
#pragma unroll
        for (int t16 = 0; t16 < 16; ++t16) {
            int col = (half * 16 + t16) * 16 + c0;
            float b = pb[col];
#pragma unroll
            for (int r = 0; r < 4; ++r)
                ot[(wave * 16 + kq * 4 + r) * 256 + t16 * 16 + c0] = acc4[half * 16 + t16][r] + b;
        }
        __syncthreads();
        for (int i = tid; i < 4096; i += 256) {
            int row = i >> 6, c = i & 63;
            *(float4*)(out + (size_t)(m0 + row) * 512 + half * 256 + c * 4) = ((const float4*)ot)[i];
        }
    }
}

// ===========================================================================
extern "C" void kernel_launch(void* const* d_in, const int* in_sizes, int n_in,
                              void* d_out, int out_size, void* d_ws, size_t ws_size,
                              hipStream_t stream) {
    const float* feat = (const float*)d_in[0];
    const float* cw[7];
    const float* cb[7];
    for (int f = 0; f < 7; ++f) {
        cw[f] = (const float*)d_in[1 + 2 * f];
        cb[f] = (const float*)d_in[2 + 2 * f];
    }
    const float* hw_w1 = (const float*)d_in[15];
    const float* hw_b1 = (const float*)d_in[16];
    const float* hw_w2 = (const float*)d_in[17];
    const float* hw_b2 = (const float*)d_in[18];
    const float* pw    = (const float*)d_in[19];
    const float* pb    = (const float*)d_in[20];
    float* out = (float*)d_out;

    char* ws = (char*)d_ws;
    unsigned short* WC  = (unsigned short*)ws;                  // 524,288 B (16 x 32KB padded)
    unsigned short* W1s = (unsigned short*)(ws + 524288);       //  65,536 B (4 x 16KB padded)
    unsigned short* W2s = (unsigned short*)(ws + 589824);       //  65,536 B
    unsigned short* Ps  = (unsigned short*)(ws + 655360);       // 131,072 B

    prep_kernel<<<1440, 256, 0, stream>>>(cw[0], cw[1], cw[2], cw[3], cw[4], cw[5], cw[6],
                                          hw_w1, hw_w2, pw, WC, W1s, W2s, Ps);
    fused_kernel<<<512, 256, 0, stream>>>(feat, WC, cb[0], cb[1], cb[2], cb[3], cb[4], cb[5], cb[6],
                                          W1s, W2s, Ps, hw_b1, hw_b2, pb, out);
}

// Round 4
// 191.730 us; speedup vs baseline: 1.0480x; 1.0020x over previous
//
#include <hip/hip_runtime.h>

typedef __attribute__((ext_vector_type(8))) short short8;
typedef __attribute__((ext_vector_type(4))) float f32x4;

#define KDIM 512
#define NCT  30            // conv n-tiles (480 cols; chunk padded to 32 tiles)
#define CB_STRIDE 97       // epilogue dump buffer stride (floats), 6-tile max phase
#define HT_OFF    28672    // ht byte offset in LDS
#define HT_STRIDE 132      // ht row stride in shorts (264 B, bank-conflict-free)
#define RING_CH   8192     // tail ring chunk bytes

// ---- bf16 helpers (RNE) ----
__device__ __forceinline__ unsigned short f2bf(float x) {
    unsigned u = __float_as_uint(x);
    return (unsigned short)((u + 0x7FFFu + ((u >> 16) & 1u)) >> 16);
}
__device__ __forceinline__ float bf2f(unsigned short h) {
    return __uint_as_float(((unsigned)h) << 16);
}

// ---- async global->LDS 16B stage: g is per-lane, l is wave-uniform base ----
__device__ __forceinline__ void stage16(const void* g, void* l, int lane) {
    __builtin_amdgcn_global_load_lds(
        (const __attribute__((address_space(1))) unsigned int*)g,
        (__attribute__((address_space(3))) unsigned int*)l, 16, 0, 0);
}

// ===========================================================================
// Prep: swizzle all weights into MFMA B-fragment order (bf16).
// Conv WC: 16 chunks x 16384 shorts (32 tiles, 30 valid).
// W1/W2: 8 chunks x 4096 shorts; chunk c = kq*2 + nhalf, 7 valid tiles + 1 pad.
// PW: 16 chunks x 4096 shorts; chunk c = kq*4 + neighth, 8 tiles (no pad).
// ===========================================================================
__global__ void prep_kernel(const float* __restrict__ w1, const float* __restrict__ w2,
                            const float* __restrict__ w3, const float* __restrict__ w4,
                            const float* __restrict__ w5, const float* __restrict__ w6,
                            const float* __restrict__ w7, const float* __restrict__ hw1,
                            const float* __restrict__ hw2, const float* __restrict__ pw,
                            unsigned short* __restrict__ WC, unsigned short* __restrict__ W1s,
                            unsigned short* __restrict__ W2s, unsigned short* __restrict__ Ps) {
    int gid = blockIdx.x * 256 + threadIdx.x;
    if (gid < 245760) {                      // conv: 512*480
        int k = gid / 480, col = gid % 480;
        const float* wp; int cbnd, NP, C, W;
        if (col < 32)       { wp = w1; cbnd = 0;   NP = 8; C = 4;  W = 1; }
        else if (col < 96)  { wp = w2; cbnd = 32;  NP = 7; C = 8;  W = 2; }
        else if (col < 176) { wp = w3; cbnd = 96;  NP = 6; C = 12; W = 3; }
        else if (col < 256) { wp = w4; cbnd = 176; NP = 5; C = 16; W = 4; }
        else if (col < 336) { wp = w5; cbnd = 256; NP = 4; C = 20; W = 5; }
        else if (col < 416) { wp = w6; cbnd = 336; NP = 3; C = 24; W = 6; }
        else                { wp = w7; cbnd = 416; NP = 2; C = 28; W = 7; }
        int c2 = col - cbnd, oc = c2 / NP, p = c2 - oc * NP;
        int j = k >> 6, e = k & 63, dk = j - p;
        float v = 0.f;
        if (oc < C && dk >= 0 && dk < W) v = wp[(oc * 64 + e) * W + dk];
        int q = k >> 5, kr = k & 31;
        WC[q * 16384 + ((col >> 4) * 64 + ((kr >> 3) * 16 + (col & 15))) * 8 + (kr & 7)] = f2bf(v);
    } else if (gid < 245760 + 57344) {       // highway: 2 x (128*224)
        int x = gid - 245760;
        const float* src = (x < 28672) ? hw1 : hw2;
        unsigned short* dst = (x < 28672) ? W1s : W2s;
        if (x >= 28672) x -= 28672;
        int k = x / 224, n = x % 224;
        float v = (k < 112) ? src[n * 112 + k] : 0.f;
        int q = k >> 5, kr = k & 31;
        int h = (n >= 112) ? 1 : 0;
        int tt = (n >> 4) - h * 7;
        dst[(q * 2 + h) * 4096 + (tt * 64 + ((kr >> 3) * 16 + (n & 15))) * 8 + (kr & 7)] = f2bf(v);
    } else if (gid < 245760 + 57344 + 65536) { // proj: 128*512
        int x = gid - 303104;
        int k = x / 512, n = x % 512;
        float v = (k < 112) ? pw[n * 112 + k] : 0.f;
        int q = k >> 5, kr = k & 31;
        int c = q * 4 + (n >> 7);
        int tt = (n >> 4) & 7;
        Ps[c * 4096 + (tt * 64 + ((kr >> 3) * 16 + (n & 15))) * 8 + (kr & 7)] = f2bf(v);
    }
}

// ===========================================================================
// Fused kernel: 512 threads / 8 waves, 128 rows per block, 256 blocks (1/CU).
// Wave w owns rows w*16..w*16+15. Conv: counted-vmcnt dbuf (2x32KB).
// Tail: one 32-chunk stream (W1 x8, W2 x8, PW x16) through a 3-deep 8KB ring,
// depth-2 prefetch with vmcnt(2); epilogues overlap in-flight prefetches.
// LDS (65536 B):
//   conv  : dbuf [0,65536)
//   epi1  : Cb [0,24832) f32 stride 97 (64 rows/group); ht @28672 (33792 B)
//   tail  : ring 3x8192 @[0,24576); ht persists
//   epi4  : ot [0,65536) f32 (ht dead), 4 col-quarters
// ===========================================================================
template <int T0, int NT>
__device__ __forceinline__ void dump_phase(float* Cb, const f32x4* acc, int w4, int lane) {
    int r0 = w4 * 16 + ((lane >> 4) * 4);
    int c0 = lane & 15;
#pragma unroll
    for (int tt = 0; tt < NT; ++tt)
#pragma unroll
        for (int r = 0; r < 4; ++r)
            Cb[(r0 + r) * CB_STRIDE + tt * 16 + c0] = acc[T0 + tt][r];
}

__device__ void reduce_phase(const float* Cb, unsigned short* ht, int tid,
                             int cA, int NPA, int choffA, int colbA, const float* cbA,
                             int cB, int NPB, int choffB, int colbB, const float* cbB) {
    int noc = cA + cB;
    for (int idx = tid; idx < 64 * noc; idx += 512) {
        int row = idx & 63, ocp = idx >> 6;
        bool isB = ocp >= cA;
        int oc = isB ? ocp - cA : ocp;
        int NP = isB ? NPB : NPA;
        int colb = isB ? colbB : colbA;
        int choff = isB ? choffB : choffA;
        const float* cb = isB ? cbB : cbA;
        const float* src = Cb + row * CB_STRIDE + colb + oc * NP;
        float m = src[0];
        for (int k = 1; k < NP; ++k) m = fmaxf(m, src[k]);
        float v = fmaxf(m + cb[oc], 0.f);
        ht[row * HT_STRIDE + choff + oc] = f2bf(v);
    }
}

template <int T0, int NT>
__device__ __forceinline__ void epi_phase(float* Cb, unsigned short* ht, const f32x4* acc,
                                          int tid, int wave, int lane,
                                          int cA, int NPA, int choffA, int colbA, const float* cbA,
                                          int cB, int NPB, int choffB, int colbB, const float* cbB) {
    for (int g = 0; g < 2; ++g) {
        if ((wave >> 2) == g) dump_phase<T0, NT>(Cb, acc, wave & 3, lane);
        __syncthreads();
        reduce_phase(Cb, ht + g * 64 * HT_STRIDE, tid,
                     cA, NPA, choffA, colbA, cbA, cB, NPB, choffB, colbB, cbB);
        __syncthreads();
    }
}

__global__ __launch_bounds__(512, 2) void fused_kernel(
        const float* __restrict__ feat, const unsigned short* __restrict__ WC,
        const float* cb0, const float* cb1, const float* cb2, const float* cb3,
        const float* cb4, const float* cb5, const float* cb6,
        const unsigned short* __restrict__ W1, const unsigned short* __restrict__ W2,
        const unsigned short* __restrict__ PW,
        const float* __restrict__ hb1, const float* __restrict__ hb2,
        const float* __restrict__ pb, float* __restrict__ out) {
    __shared__ __align__(16) char sm[65536];
    const int tid = threadIdx.x, lane = tid & 63, wave = tid >> 6;
    const int c0 = lane & 15, kq = lane >> 4;
    const int m0 = blockIdx.x * 128;
    f32x4 zero = {0.f, 0.f, 0.f, 0.f};

    // ---------------- conv GEMM: A-frags (16 k-chunks) in registers ----------------
    const float* arow = feat + (size_t)(m0 + wave * 16 + c0) * KDIM + kq * 8;
    short8 af[16];
#pragma unroll
    for (int q = 0; q < 16; ++q) {
        float t[8];
        *(float4*)(t)     = *(const float4*)(arow + q * 32);
        *(float4*)(t + 4) = *(const float4*)(arow + q * 32 + 4);
        short8 v;
#pragma unroll
        for (int i = 0; i < 8; ++i) v[i] = (short)f2bf(t[i]);
        af[q] = v;
    }

    f32x4 acc[NCT];
#pragma unroll
    for (int t = 0; t < NCT; ++t) acc[t] = zero;

    // prologue: stage chunk 0 into buf 0 (4 loads/thread, uniform)
    for (int i = tid; i < 2048; i += 512)
        stage16(WC + i * 8, sm + (i - lane) * 16, lane);

#pragma unroll
    for (int q = 0; q < 16; ++q) {
        if (q < 15) {
            const unsigned short* src = WC + (q + 1) * 16384;
            char* dst = sm + ((q + 1) & 1) * 32768;
            for (int i = tid; i < 2048; i += 512)
                stage16(src + i * 8, dst + (i - lane) * 16, lane);
            asm volatile("s_waitcnt vmcnt(4)" ::: "memory");   // chunk q landed; q+1 in flight
        } else {
            asm volatile("s_waitcnt vmcnt(0)" ::: "memory");
        }
        __builtin_amdgcn_s_barrier();
        const char* bb = sm + (q & 1) * 32768;
#pragma unroll
        for (int t = 0; t < NCT; ++t) {
            short8 b = *(const short8*)(bb + (t * 64 + lane) * 16);
            acc[t] = __builtin_amdgcn_mfma_f32_16x16x32_bf16(af[q], b, acc[t], 0, 0, 0);
        }
        asm volatile("s_waitcnt lgkmcnt(0)" ::: "memory");     // buf reads done
        __builtin_amdgcn_s_barrier();                          // safe to restage
    }

    // ---------------- conv epilogue: 6 filter-aligned phases x 2 row-groups ----------------
    float* Cb = (float*)sm;
    unsigned short* ht = (unsigned short*)(sm + HT_OFF);   // 128 rows x 132 shorts
    for (int i = tid; i < 2048; i += 512)                  // zero K-pad cols 112..127
        ht[(i >> 4) * HT_STRIDE + 112 + (i & 15)] = 0;
    __syncthreads();
    epi_phase<0, 6>(Cb, ht, acc, tid, wave, lane, 4, 8, 0, 0, cb0, 8, 7, 4, 32, cb1);
    epi_phase<6, 5>(Cb, ht, acc, tid, wave, lane, 12, 6, 12, 0, cb2, 0, 1, 0, 0, cb2);
    epi_phase<11, 5>(Cb, ht, acc, tid, wave, lane, 16, 5, 24, 0, cb3, 0, 1, 0, 0, cb3);
    epi_phase<16, 5>(Cb, ht, acc, tid, wave, lane, 20, 4, 40, 0, cb4, 0, 1, 0, 0, cb4);
    epi_phase<21, 5>(Cb, ht, acc, tid, wave, lane, 24, 3, 60, 0, cb5, 0, 1, 0, 0, cb5);
    epi_phase<26, 4>(Cb, ht, acc, tid, wave, lane, 28, 2, 84, 0, cb6, 0, 1, 0, 0, cb6);
    // ht complete; Cb dead

    // ---------------- tail: 32-chunk stream through 3-deep ring ----------------
    char* ring = sm;
    short8 a2[4];
#pragma unroll
    for (int q = 0; q < 4; ++q)
        a2[q] = *(const short8*)((const char*)ht + (wave * 16 + c0) * 264 + q * 64 + kq * 16);

    // prologue: chunks 0,1 (W1) into ring 0,1 — 1 load/thread each
    stage16(W1 + tid * 8, ring + (tid - lane) * 16, lane);
    stage16(W1 + 4096 + tid * 8, ring + RING_CH + (tid - lane) * 16, lane);

    // ---- GEMM2 (highway1): global chunks 0..7 ----
    f32x4 acc2[14];
#pragma unroll
    for (int t = 0; t < 14; ++t) acc2[t] = zero;
#pragma unroll
    for (int i = 0; i < 8; ++i) {
        {   // stage global chunk i+2 (W1 or first W2 chunks)
            const unsigned short* src = (i < 6) ? (W1 + (i + 2) * 4096) : (W2 + (i - 6) * 4096);
            char* dst = ring + ((i + 2) % 3) * RING_CH;
            stage16(src + tid * 8, dst + (tid - lane) * 16, lane);
        }
        asm volatile("s_waitcnt vmcnt(2)" ::: "memory");
        __builtin_amdgcn_s_barrier();
        const char* bb = ring + (i % 3) * RING_CH;
        const int q = i >> 1, h = i & 1;
#pragma unroll
        for (int tt = 0; tt < 7; ++tt) {
            short8 b = *(const short8*)(bb + (tt * 64 + lane) * 16);
            acc2[h * 7 + tt] = __builtin_amdgcn_mfma_f32_16x16x32_bf16(a2[q], b, acc2[h * 7 + tt], 0, 0, 0);
        }
        asm volatile("s_waitcnt lgkmcnt(0)" ::: "memory");
        __builtin_amdgcn_s_barrier();
    }

    // epilogue2 -> ht in place (W2 chunks 0,1 in flight meanwhile)
#pragma unroll
    for (int t = 0; t < 14; ++t) {
        float bp = hb1[t * 16 + c0], bg = hb1[112 + t * 16 + c0];
        (void)bg;
#pragma unroll
        for (int r = 0; r < 4; ++r) {
            int row = wave * 16 + kq * 4 + r;
            int col = t * 16 + c0;
            if (t < 7) {
                float px = acc2[t][r] + bp;
                float gt = acc2[t + 7][r] + hb1[112 + t * 16 + c0];
                float g = 1.f / (1.f + __expf(-gt));
                float hres = bf2f(ht[row * HT_STRIDE + col]);
                ht[row * HT_STRIDE + col] = f2bf(g * hres + (1.f - g) * fmaxf(px, 0.f));
            }
        }
    }
    asm volatile("s_waitcnt lgkmcnt(0)" ::: "memory");
    __builtin_amdgcn_s_barrier();

    // ---- GEMM3 (highway2): global chunks 8..15 ----
    short8 a3[4];
#pragma unroll
    for (int q = 0; q < 4; ++q)
        a3[q] = *(const short8*)((const char*)ht + (wave * 16 + c0) * 264 + q * 64 + kq * 16);

    f32x4 acc3[14];
#pragma unroll
    for (int t = 0; t < 14; ++t) acc3[t] = zero;
#pragma unroll
    for (int j = 0; j < 8; ++j) {
        {   // stage global chunk j+10 (W2 tail or first PW chunks)
            const unsigned short* src = (j < 6) ? (W2 + (j + 2) * 4096) : (PW + (j - 6) * 4096);
            char* dst = ring + ((j + 10) % 3) * RING_CH;
            stage16(src + tid * 8, dst + (tid - lane) * 16, lane);
        }
        asm volatile("s_waitcnt vmcnt(2)" ::: "memory");
        __builtin_amdgcn_s_barrier();
        const char* bb = ring + ((j + 8) % 3) * RING_CH;
        const int q = j >> 1, h = j & 1;
#pragma unroll
        for (int tt = 0; tt < 7; ++tt) {
            short8 b = *(const short8*)(bb + (tt * 64 + lane) * 16);
            acc3[h * 7 + tt] = __builtin_amdgcn_mfma_f32_16x16x32_bf16(a3[q], b, acc3[h * 7 + tt], 0, 0, 0);
        }
        asm volatile("s_waitcnt lgkmcnt(0)" ::: "memory");
        __builtin_amdgcn_s_barrier();
    }

    // epilogue3 -> ht in place (PW chunks 0,1 in flight meanwhile)
#pragma unroll
    for (int t = 0; t < 7; ++t) {
        float bp = hb2[t * 16 + c0], bg = hb2[112 + t * 16 + c0];
#pragma unroll
        for (int r = 0; r < 4; ++r) {
            int row = wave * 16 + kq * 4 + r;
            int col = t * 16 + c0;
            float px = acc3[t][r] + bp;
            float gt = acc3[t + 7][r] + bg;
            float g = 1.f / (1.f + __expf(-gt));
            float hres = bf2f(ht[row * HT_STRIDE + col]);
            ht[row * HT_STRIDE + col] = f2bf(g * hres + (1.f - g) * fmaxf(px, 0.f));
        }
    }
    asm volatile("s_waitcnt lgkmcnt(0)" ::: "memory");
    __builtin_amdgcn_s_barrier();

    // ---- GEMM4 (proj): global chunks 16..31 ----
    short8 a4[4];
#pragma unroll
    for (int q = 0; q < 4; ++q)
        a4[q] = *(const short8*)((const char*)ht + (wave * 16 + c0) * 264 + q * 64 + kq * 16);

    f32x4 acc4[32];
#pragma unroll
    for (int t = 0; t < 32; ++t) acc4[t] = zero;
#pragma unroll
    for (int k = 0; k < 16; ++k) {
        if (k < 14) {
            const unsigned short* src = PW + (k + 2) * 4096;
            char* dst = ring + ((k + 18) % 3) * RING_CH;
            stage16(src + tid * 8, dst + (tid - lane) * 16, lane);
            asm volatile("s_waitcnt vmcnt(2)" ::: "memory");
        } else if (k == 14) {
            asm volatile("s_waitcnt vmcnt(1)" ::: "memory");
        } else {
            asm volatile("s_waitcnt vmcnt(0)" ::: "memory");
        }
        __builtin_amdgcn_s_barrier();
        const char* bb = ring + ((k + 16) % 3) * RING_CH;
        const int q = k >> 2, e = k & 3;
#pragma unroll
        for (int tt = 0; tt < 8; ++tt) {
            short8 b = *(const short8*)(bb + (tt * 64 + lane) * 16);
            acc4[e * 8 + tt] = __builtin_amdgcn_mfma_f32_16x16x32_bf16(a4[q], b, acc4[e * 8 + tt], 0, 0, 0);
        }
        asm volatile("s_waitcnt lgkmcnt(0)" ::: "memory");
        __builtin_amdgcn_s_barrier();
    }

    // ---------------- epilogue4: +bias, coalesced store, 4 col-quarters ----------------
    float* ot = (float*)sm;
#pragma unroll
    for (int e = 0; e < 4; ++e) {
        __syncthreads();
#pragma unroll
        for (int tt = 0; tt < 8; ++tt) {
            int col = e * 128 + tt * 16 + c0;
            float b = pb[col];
#pragma unroll
            for (int r = 0; r < 4; ++r)
                ot[(wave * 16 + kq * 4 + r) * 128 + tt * 16 + c0] = acc4[e * 8 + tt][r] + b;
        }
        __syncthreads();
        for (int i = tid; i < 4096; i += 512) {
            int row = i >> 5, c = i & 31;
            *(float4*)(out + (size_t)(m0 + row) * 512 + e * 128 + c * 4) = ((const float4*)ot)[i];
        }
    }
}

// ===========================================================================
extern "C" void kernel_launch(void* const* d_in, const int* in_sizes, int n_in,
                              void* d_out, int out_size, void* d_ws, size_t ws_size,
                              hipStream_t stream) {
    const float* feat = (const float*)d_in[0];
    const float* cw[7];
    const float* cb[7];
    for (int f = 0; f < 7; ++f) {
        cw[f] = (const float*)d_in[1 + 2 * f];
        cb[f] = (const float*)d_in[2 + 2 * f];
    }
    const float* hw_w1 = (const float*)d_in[15];
    const float* hw_b1 = (const float*)d_in[16];
    const float* hw_w2 = (const float*)d_in[17];
    const float* hw_b2 = (const float*)d_in[18];
    const float* pw    = (const float*)d_in[19];
    const float* pb    = (const float*)d_in[20];
    float* out = (float*)d_out;

    char* ws = (char*)d_ws;
    unsigned short* WC  = (unsigned short*)ws;                  // 524,288 B (16 x 32KB)
    unsigned short* W1s = (unsigned short*)(ws + 524288);       //  65,536 B (8 x 8KB)
    unsigned short* W2s = (unsigned short*)(ws + 589824);       //  65,536 B
    unsigned short* Ps  = (unsigned short*)(ws + 655360);       // 131,072 B (16 x 8KB)

    prep_kernel<<<1440, 256, 0, stream>>>(cw[0], cw[1], cw[2], cw[3], cw[4], cw[5], cw[6],
                                          hw_w1, hw_w2, pw, WC, W1s, W2s, Ps);
    fused_kernel<<<256, 512, 0, stream>>>(feat, WC, cb[0], cb[1], cb[2], cb[3], cb[4], cb[5], cb[6],
                                          W1s, W2s, Ps, hw_b1, hw_b2, pb, out);
}